// Round 4
// baseline (165.923 us; speedup 1.0000x reference)
//
#include <hip/hip_runtime.h>

#define BB 2
#define CC 64
#define HH 128
#define WW 128
#define OC 64
#define HW (HH * WW)

struct Meta { int i0, i1, i2, i3; float w0, w1, w2, w3; int dst; };

// ---------------- shared device helpers ----------------

__device__ __forceinline__ void offset_phase(
    const float* __restrict__ x, const float* __restrict__ Wp,
    const float* __restrict__ bp, float* __restrict__ smem,
    int b, int i, int j0, int t, Meta& M0, Meta& M1)
{
    // phase 0a: offset-conv partials into smem[8 grp][32 pos][18]
    {
        const int grp = t >> 5;
        const int pp  = t & 31;
        const int j   = j0 + pp;
        float part[18];
#pragma unroll
        for (int o = 0; o < 18; ++o) part[o] = 0.f;
        const float* xg = x + (b * CC + grp * 8) * HW;
        for (int c = 0; c < 8; ++c) {
            float xv[9];
#pragma unroll
            for (int dx = 0; dx < 3; ++dx) {
                const int ii = i + dx - 1;
                const bool okx = (unsigned)ii < (unsigned)HH;
#pragma unroll
                for (int dy = 0; dy < 3; ++dy) {
                    const int jj = j + dy - 1;
                    const bool ok = okx && ((unsigned)jj < (unsigned)WW);
                    xv[dx * 3 + dy] = ok ? xg[c * HW + ii * WW + jj] : 0.f;
                }
            }
            const float* wp = Wp + (grp * 8 + c) * 9;
#pragma unroll
            for (int o = 0; o < 18; ++o) {
                const float* w = wp + o * 576;
#pragma unroll
                for (int k = 0; k < 9; ++k)
                    part[o] = fmaf(xv[k], w[k], part[o]);
            }
        }
#pragma unroll
        for (int o = 0; o < 18; ++o)
            smem[grp * 576 + pp * 18 + o] = part[o];
    }
    __syncthreads();

    // phase 0b: sampling metadata
    auto mkmeta = [&](int pos, int n) -> Meta {
        const int kx = n / 3, ky = n - kx * 3;
        float offx = bp[n], offy = bp[9 + n];
#pragma unroll
        for (int g = 0; g < 8; ++g) {
            offx += smem[g * 576 + pos * 18 + n];
            offy += smem[g * 576 + pos * 18 + 9 + n];
        }
        const float px = offx + (float)(kx - 1) + (float)(i + 1);
        const float py = offy + (float)(ky - 1) + (float)(j0 + pos + 1);
        const float flx = floorf(px), fly = floorf(py);
        const float qltx = fminf(fmaxf(flx,       0.f), 129.f);
        const float qlty = fminf(fmaxf(fly,       0.f), 129.f);
        const float qrbx = fminf(fmaxf(flx + 1.f, 0.f), 129.f);
        const float qrby = fminf(fmaxf(fly + 1.f, 0.f), 129.f);
        const float pxc  = fminf(fmaxf(px, 0.f), 129.f);
        const float pyc  = fminf(fmaxf(py, 0.f), 129.f);
        const float gx0 = 1.f + (qltx - pxc), gx1 = 1.f - (qrbx - pxc);
        const float gy0 = 1.f + (qlty - pyc), gy1 = 1.f - (qrby - pyc);
        const int rx0 = (int)qltx - 1, rx1 = (int)qrbx - 1;
        const int ry0 = (int)qlty - 1, ry1 = (int)qrby - 1;
        const bool vx0 = (unsigned)rx0 < (unsigned)HH, vx1 = (unsigned)rx1 < (unsigned)HH;
        const bool vy0 = (unsigned)ry0 < (unsigned)WW, vy1 = (unsigned)ry1 < (unsigned)WW;
        Meta M;
        M.i0 = (vx0 && vy0) ? rx0 * WW + ry0 : 0;  M.w0 = (vx0 && vy0) ? gx0 * gy0 : 0.f;
        M.i1 = (vx1 && vy1) ? rx1 * WW + ry1 : 0;  M.w1 = (vx1 && vy1) ? gx1 * gy1 : 0.f;
        M.i2 = (vx0 && vy1) ? rx0 * WW + ry1 : 0;  M.w2 = (vx0 && vy1) ? gx0 * gy1 : 0.f;
        M.i3 = (vx1 && vy0) ? rx1 * WW + ry0 : 0;  M.w3 = (vx1 && vy0) ? gx1 * gy0 : 0.f;
        M.dst = n * 32 + pos;
        return M;
    };

    M0 = mkmeta(t & 31, t >> 5);
    M1.i0 = M1.i1 = M1.i2 = M1.i3 = 0;
    M1.w0 = M1.w1 = M1.w2 = M1.w3 = 0.f; M1.dst = 0;
    if (t < 32) M1 = mkmeta(t, 8);
    __syncthreads();
}

// ---------------- Wc transpose: Wt[(c*9+n)][oc] ----------------

__global__ __launch_bounds__(256) void wt_transpose(const float* __restrict__ Wc,
                                                    float* __restrict__ Wt)
{
    const int id = blockIdx.x * 256 + threadIdx.x;   // id = oc*576 + k (coalesced read)
    if (id < OC * 576) {
        const int oc = id / 576;
        const int k  = id - oc * 576;
        Wt[k * 64 + oc] = Wc[id];
    }
}

// ---------------- main fused kernel (pipelined, Wt path) ----------------

__global__ __launch_bounds__(256) void dcn_fused4(
    const float* __restrict__ x,
    const float* __restrict__ Wp,
    const float* __restrict__ bp,
    const float* __restrict__ Wt,
    float* __restrict__ out)
{
    __shared__ __align__(16) float smem[4608];

    const int t  = threadIdx.x;
    const int bx = blockIdx.x;
    const int b  = bx >> 9;
    const int i  = (bx >> 2) & 127;
    const int j0 = (bx & 3) << 5;

    Meta M0, M1;
    offset_phase(x, Wp, bp, smem, b, i, j0, t, M0, M1);

    float acc[4][2];
#pragma unroll
    for (int m = 0; m < 4; ++m) { acc[m][0] = 0.f; acc[m][1] = 0.f; }

    const int oc4  = (t >> 4) << 2;
    const int pos2 = (t & 15) << 1;
    const bool hi  = (t < 32);
    const float* xb = x + b * (CC * HW);

    float* const sX0 = smem;            // 576 floats
    float* const sX1 = smem + 576;
    float* const sW0 = smem + 1152;     // 1152 floats
    float* const sW1 = smem + 2304;

    auto gemm = [&](const float* bX, const float* bW) {
#pragma unroll
        for (int ch = 0; ch < 2; ++ch)
#pragma unroll
            for (int n = 0; n < 9; ++n) {
                const float4 wr = *(const float4*)&bW[ch * 576 + n * 64 + oc4];
                const float2 xr = *(const float2*)&bX[ch * 288 + n * 32 + pos2];
                acc[0][0] = fmaf(wr.x, xr.x, acc[0][0]);
                acc[0][1] = fmaf(wr.x, xr.y, acc[0][1]);
                acc[1][0] = fmaf(wr.y, xr.x, acc[1][0]);
                acc[1][1] = fmaf(wr.y, xr.y, acc[1][1]);
                acc[2][0] = fmaf(wr.z, xr.x, acc[2][0]);
                acc[2][1] = fmaf(wr.z, xr.y, acc[2][1]);
                acc[3][0] = fmaf(wr.w, xr.x, acc[3][0]);
                acc[3][1] = fmaf(wr.w, xr.y, acc[3][1]);
            }
    };

    // stage chunk (c0,c0+1) directly (prologue, no overlap)
    auto stage0 = [&](int c0, float* bX, float* bW) {
        const float* xcA = xb + c0 * HW;
        const float* xcB = xcA + HW;
        float v = xcA[M0.i0] * M0.w0;
        v = fmaf(xcA[M0.i1], M0.w1, v);
        v = fmaf(xcA[M0.i2], M0.w2, v);
        v = fmaf(xcA[M0.i3], M0.w3, v);
        bX[M0.dst] = v;
        v = xcB[M0.i0] * M0.w0;
        v = fmaf(xcB[M0.i1], M0.w1, v);
        v = fmaf(xcB[M0.i2], M0.w2, v);
        v = fmaf(xcB[M0.i3], M0.w3, v);
        bX[288 + M0.dst] = v;
        if (hi) {
            v = xcA[M1.i0] * M1.w0;
            v = fmaf(xcA[M1.i1], M1.w1, v);
            v = fmaf(xcA[M1.i2], M1.w2, v);
            v = fmaf(xcA[M1.i3], M1.w3, v);
            bX[M1.dst] = v;
            v = xcB[M1.i0] * M1.w0;
            v = fmaf(xcB[M1.i1], M1.w1, v);
            v = fmaf(xcB[M1.i2], M1.w2, v);
            v = fmaf(xcB[M1.i3], M1.w3, v);
            bX[288 + M1.dst] = v;
            *(float4*)&bW[1024 + t * 4] = *(const float4*)&Wt[c0 * 576 + 1024 + t * 4];
        }
        *(float4*)&bW[t * 4] = *(const float4*)&Wt[c0 * 576 + t * 4];
    };

    // pipelined round: issue loads for chunk c0 -> gemm current -> combine+write next
    auto pipe = [&](int c0, const float* gX, const float* gW, float* bX, float* bW) {
        const float* xcA = xb + c0 * HW;
        const float* xcB = xcA + HW;
        float gA0 = xcA[M0.i0], gA1 = xcA[M0.i1], gA2 = xcA[M0.i2], gA3 = xcA[M0.i3];
        float gB0 = xcB[M0.i0], gB1 = xcB[M0.i1], gB2 = xcB[M0.i2], gB3 = xcB[M0.i3];
        float hA0 = 0.f, hA1 = 0.f, hA2 = 0.f, hA3 = 0.f;
        float hB0 = 0.f, hB1 = 0.f, hB2 = 0.f, hB3 = 0.f;
        float4 w1 = make_float4(0.f, 0.f, 0.f, 0.f);
        if (hi) {
            hA0 = xcA[M1.i0]; hA1 = xcA[M1.i1]; hA2 = xcA[M1.i2]; hA3 = xcA[M1.i3];
            hB0 = xcB[M1.i0]; hB1 = xcB[M1.i1]; hB2 = xcB[M1.i2]; hB3 = xcB[M1.i3];
            w1 = *(const float4*)&Wt[c0 * 576 + 1024 + t * 4];
        }
        const float4 w0 = *(const float4*)&Wt[c0 * 576 + t * 4];
        __builtin_amdgcn_sched_barrier(0);   // keep load issue above the GEMM

        gemm(gX, gW);                        // lgkmcnt only; vmem stays in flight

        __builtin_amdgcn_sched_barrier(0);   // keep combine/write below the GEMM
        float v = gA0 * M0.w0;
        v = fmaf(gA1, M0.w1, v); v = fmaf(gA2, M0.w2, v); v = fmaf(gA3, M0.w3, v);
        bX[M0.dst] = v;
        v = gB0 * M0.w0;
        v = fmaf(gB1, M0.w1, v); v = fmaf(gB2, M0.w2, v); v = fmaf(gB3, M0.w3, v);
        bX[288 + M0.dst] = v;
        *(float4*)&bW[t * 4] = w0;
        if (hi) {
            v = hA0 * M1.w0;
            v = fmaf(hA1, M1.w1, v); v = fmaf(hA2, M1.w2, v); v = fmaf(hA3, M1.w3, v);
            bX[M1.dst] = v;
            v = hB0 * M1.w0;
            v = fmaf(hB1, M1.w1, v); v = fmaf(hB2, M1.w2, v); v = fmaf(hB3, M1.w3, v);
            bX[288 + M1.dst] = v;
            *(float4*)&bW[1024 + t * 4] = w1;
        }
    };

    stage0(0, sX0, sW0);
    __syncthreads();
    for (int k = 0; k < 30; k += 2) {
        pipe(2 * (k + 1), sX0, sW0, sX1, sW1);  // gemm chunk k, stage k+1
        __syncthreads();
        pipe(2 * (k + 2), sX1, sW1, sX0, sW0);  // gemm chunk k+1, stage k+2
        __syncthreads();
    }
    pipe(62, sX0, sW0, sX1, sW1);               // gemm chunk 30, stage chunk 31
    __syncthreads();
    gemm(sX1, sW1);                             // chunk 31

#pragma unroll
    for (int m = 0; m < 4; ++m) {
        float2 v = make_float2(acc[m][0], acc[m][1]);
        *reinterpret_cast<float2*>(&out[((b * OC + oc4 + m) * HH + i) * WW + j0 + pos2]) = v;
    }
}

// ---------------- fallback (R3 structure, reads Wc directly) ----------------

__global__ __launch_bounds__(256) void dcn_fused3(
    const float* __restrict__ x,
    const float* __restrict__ Wp,
    const float* __restrict__ bp,
    const float* __restrict__ Wc,
    float* __restrict__ out)
{
    __shared__ __align__(16) float smem[4608];
    const int t  = threadIdx.x;
    const int bx = blockIdx.x;
    const int b  = bx >> 9;
    const int i  = (bx >> 2) & 127;
    const int j0 = (bx & 3) << 5;

    Meta M0, M1;
    offset_phase(x, Wp, bp, smem, b, i, j0, t, M0, M1);

    float acc[4][2];
#pragma unroll
    for (int m = 0; m < 4; ++m) { acc[m][0] = 0.f; acc[m][1] = 0.f; }
    const int oc4  = (t >> 4) << 2;
    const int pos2 = (t & 15) << 1;
    const int woc  = t & 63;
    const int g    = __builtin_amdgcn_readfirstlane(t >> 6);
    const int r0   = (g < 2) ? g * 5 : 10 + (g - 2) * 4;
    const int rc   = (g < 2) ? 5 : 4;
    const float* xb = x + b * (CC * HW);

    auto stage = [&](int k, int d) {
        const float* xc0 = xb + (2 * k) * HW;
        float* bX = smem + d * 576;
        float* bW = smem + 1152 + d * 1152;
#pragma unroll
        for (int ch = 0; ch < 2; ++ch) {
            const float* xc = xc0 + ch * HW;
            float v = xc[M0.i0] * M0.w0;
            v = fmaf(xc[M0.i1], M0.w1, v);
            v = fmaf(xc[M0.i2], M0.w2, v);
            v = fmaf(xc[M0.i3], M0.w3, v);
            bX[ch * 288 + M0.dst] = v;
        }
        if (t < 32) {
#pragma unroll
            for (int ch = 0; ch < 2; ++ch) {
                const float* xc = xc0 + ch * HW;
                float v = xc[M1.i0] * M1.w0;
                v = fmaf(xc[M1.i1], M1.w1, v);
                v = fmaf(xc[M1.i2], M1.w2, v);
                v = fmaf(xc[M1.i3], M1.w3, v);
                bX[ch * 288 + M1.dst] = v;
            }
        }
#pragma unroll
        for (int q = 0; q < 5; ++q) {
            if (q < rc) {
                const int r  = r0 + q;
                const int ch = (r >= 9) ? 1 : 0;
                const int n  = r - ch * 9;
                bW[ch * 576 + n * 64 + woc] = Wc[woc * 576 + (2 * k + ch) * 9 + n];
            }
        }
    };
    auto gemm = [&](int d) {
        const float* bX = smem + d * 576;
        const float* bW = smem + 1152 + d * 1152;
#pragma unroll
        for (int ch = 0; ch < 2; ++ch)
#pragma unroll
            for (int n = 0; n < 9; ++n) {
                const float4 wr = *(const float4*)&bW[ch * 576 + n * 64 + oc4];
                const float2 xr = *(const float2*)&bX[ch * 288 + n * 32 + pos2];
                acc[0][0] = fmaf(wr.x, xr.x, acc[0][0]);
                acc[0][1] = fmaf(wr.x, xr.y, acc[0][1]);
                acc[1][0] = fmaf(wr.y, xr.x, acc[1][0]);
                acc[1][1] = fmaf(wr.y, xr.y, acc[1][1]);
                acc[2][0] = fmaf(wr.z, xr.x, acc[2][0]);
                acc[2][1] = fmaf(wr.z, xr.y, acc[2][1]);
                acc[3][0] = fmaf(wr.w, xr.x, acc[3][0]);
                acc[3][1] = fmaf(wr.w, xr.y, acc[3][1]);
            }
    };
    stage(0, 0);
    __syncthreads();
    for (int k = 0; k < 31; ++k) {
        stage(k + 1, (k + 1) & 1);
        gemm(k & 1);
        __syncthreads();
    }
    gemm(1);
#pragma unroll
    for (int m = 0; m < 4; ++m) {
        float2 v = make_float2(acc[m][0], acc[m][1]);
        *reinterpret_cast<float2*>(&out[((b * OC + oc4 + m) * HH + i) * WW + j0 + pos2]) = v;
    }
}

extern "C" void kernel_launch(void* const* d_in, const int* in_sizes, int n_in,
                              void* d_out, int out_size, void* d_ws, size_t ws_size,
                              hipStream_t stream) {
    const float* x  = (const float*)d_in[0];
    const float* Wp = (const float*)d_in[1];
    const float* bp = (const float*)d_in[2];
    const float* Wc = (const float*)d_in[3];
    float* out = (float*)d_out;
    if (ws_size >= (size_t)(OC * 576 * 4)) {
        float* Wt = (float*)d_ws;
        wt_transpose<<<dim3((OC * 576 + 255) / 256), dim3(256), 0, stream>>>(Wc, Wt);
        dcn_fused4<<<dim3(BB * HH * 4), dim3(256), 0, stream>>>(x, Wp, bp, Wt, out);
    } else {
        dcn_fused3<<<dim3(BB * HH * 4), dim3(256), 0, stream>>>(x, Wp, bp, Wc, out);
    }
}

// Round 5
// 116.664 us; speedup vs baseline: 1.4222x; 1.4222x over previous
//
#include <hip/hip_runtime.h>
#include <hip/hip_bf16.h>

#define BB 2
#define CC 64
#define HH 128
#define WW 128
#define OC 64
#define HW (HH * WW)

typedef __attribute__((ext_vector_type(8))) short bf16x8;   // 8 bf16 (4 VGPRs), per guide
typedef __attribute__((ext_vector_type(4))) float f32x4;

struct Meta { int i0, i1, i2, i3; float w0, w1, w2, w3; };

__device__ __forceinline__ unsigned short bfbits(float f) {
    __hip_bfloat16 h = __float2bfloat16(f);
    return __builtin_bit_cast(unsigned short, h);
}

// ---------------- offset conv + sampling metadata (proven R3 path) ----------------

__device__ __forceinline__ void offset_phase(
    const float* __restrict__ x, const float* __restrict__ Wp,
    const float* __restrict__ bp, float* __restrict__ smem,
    int b, int i, int j0, int t, Meta& M0, Meta& M1)
{
    {
        const int grp = t >> 5;
        const int pp  = t & 31;
        const int j   = j0 + pp;
        float part[18];
#pragma unroll
        for (int o = 0; o < 18; ++o) part[o] = 0.f;
        const float* xg = x + (b * CC + grp * 8) * HW;
        for (int c = 0; c < 8; ++c) {
            float xv[9];
#pragma unroll
            for (int dx = 0; dx < 3; ++dx) {
                const int ii = i + dx - 1;
                const bool okx = (unsigned)ii < (unsigned)HH;
#pragma unroll
                for (int dy = 0; dy < 3; ++dy) {
                    const int jj = j + dy - 1;
                    const bool ok = okx && ((unsigned)jj < (unsigned)WW);
                    xv[dx * 3 + dy] = ok ? xg[c * HW + ii * WW + jj] : 0.f;
                }
            }
            const float* wp = Wp + (grp * 8 + c) * 9;
#pragma unroll
            for (int o = 0; o < 18; ++o) {
                const float* w = wp + o * 576;
#pragma unroll
                for (int k = 0; k < 9; ++k)
                    part[o] = fmaf(xv[k], w[k], part[o]);
            }
        }
#pragma unroll
        for (int o = 0; o < 18; ++o)
            smem[grp * 576 + pp * 18 + o] = part[o];
    }
    __syncthreads();

    auto mkmeta = [&](int pos, int n) -> Meta {
        const int kx = n / 3, ky = n - kx * 3;
        float offx = bp[n], offy = bp[9 + n];
#pragma unroll
        for (int g = 0; g < 8; ++g) {
            offx += smem[g * 576 + pos * 18 + n];
            offy += smem[g * 576 + pos * 18 + 9 + n];
        }
        const float px = offx + (float)(kx - 1) + (float)(i + 1);
        const float py = offy + (float)(ky - 1) + (float)(j0 + pos + 1);
        const float flx = floorf(px), fly = floorf(py);
        const float qltx = fminf(fmaxf(flx,       0.f), 129.f);
        const float qlty = fminf(fmaxf(fly,       0.f), 129.f);
        const float qrbx = fminf(fmaxf(flx + 1.f, 0.f), 129.f);
        const float qrby = fminf(fmaxf(fly + 1.f, 0.f), 129.f);
        const float pxc  = fminf(fmaxf(px, 0.f), 129.f);
        const float pyc  = fminf(fmaxf(py, 0.f), 129.f);
        const float gx0 = 1.f + (qltx - pxc), gx1 = 1.f - (qrbx - pxc);
        const float gy0 = 1.f + (qlty - pyc), gy1 = 1.f - (qrby - pyc);
        const int rx0 = (int)qltx - 1, rx1 = (int)qrbx - 1;
        const int ry0 = (int)qlty - 1, ry1 = (int)qrby - 1;
        const bool vx0 = (unsigned)rx0 < (unsigned)HH, vx1 = (unsigned)rx1 < (unsigned)HH;
        const bool vy0 = (unsigned)ry0 < (unsigned)WW, vy1 = (unsigned)ry1 < (unsigned)WW;
        Meta M;
        M.i0 = (vx0 && vy0) ? rx0 * WW + ry0 : 0;  M.w0 = (vx0 && vy0) ? gx0 * gy0 : 0.f;
        M.i1 = (vx1 && vy1) ? rx1 * WW + ry1 : 0;  M.w1 = (vx1 && vy1) ? gx1 * gy1 : 0.f;
        M.i2 = (vx0 && vy1) ? rx0 * WW + ry1 : 0;  M.w2 = (vx0 && vy1) ? gx0 * gy1 : 0.f;
        M.i3 = (vx1 && vy0) ? rx1 * WW + ry0 : 0;  M.w3 = (vx1 && vy0) ? gx1 * gy0 : 0.f;
        return M;
    };

    M0 = mkmeta(t & 31, t >> 5);   // taps 0..7, 32 channels each
    M1 = mkmeta(t & 31, 8);        // tap 8, 4-channel slice per thread
    __syncthreads();
}

// ---------------- fused kernel: VALU sampling + MFMA GEMM ----------------

__global__ __launch_bounds__(256, 4) void dcn_mfma(
    const float* __restrict__ x,
    const float* __restrict__ Wp,
    const float* __restrict__ bp,
    const float* __restrict__ Wc,
    float* __restrict__ out)
{
    // union: phase0 partials (18432 B as float) / two 18432 B bf16 B-buffers
    __shared__ __align__(16) unsigned char smraw[36864];
    float* smf = (float*)smraw;
    unsigned short* bbuf = (unsigned short*)smraw;

    const int t  = threadIdx.x;
    const int bx = blockIdx.x;
    const int b  = bx >> 9;
    const int i  = (bx >> 2) & 127;
    const int j0 = (bx & 3) << 5;

    Meta M0, M1;
    offset_phase(x, Wp, bp, smf, b, i, j0, t, M0, M1);

    const int pos = t & 31;
    const int n0  = t >> 5;            // tap for M0 staging
    const int ccb = (t >> 5) << 2;     // 4-channel window for tap-8 staging
    const float* xb = x + b * (CC * HW);

    // B layout (ushort idx): (k'>>3)*256 + pos*8 + (k'&7)  -> lane ds_read_b128
    auto stage = [&](int ch0, int dbase) {
#pragma unroll 8
        for (int cc = 0; cc < 32; ++cc) {
            const float* p = xb + (ch0 + cc) * HW;
            float v = p[M0.i0] * M0.w0;
            v = fmaf(p[M0.i1], M0.w1, v);
            v = fmaf(p[M0.i2], M0.w2, v);
            v = fmaf(p[M0.i3], M0.w3, v);
            const int kp = cc * 9 + n0;
            bbuf[dbase + ((kp >> 3) << 8) + (pos << 3) + (kp & 7)] = bfbits(v);
        }
#pragma unroll
        for (int q = 0; q < 4; ++q) {
            const int cc = ccb + q;
            const float* p = xb + (ch0 + cc) * HW;
            float v = p[M1.i0] * M1.w0;
            v = fmaf(p[M1.i1], M1.w1, v);
            v = fmaf(p[M1.i2], M1.w2, v);
            v = fmaf(p[M1.i3], M1.w3, v);
            const int kp = cc * 9 + 8;
            bbuf[dbase + ((kp >> 3) << 8) + (pos << 3) + (kp & 7)] = bfbits(v);
        }
    };

    const int w_s = __builtin_amdgcn_readfirstlane(t >> 6);  // wave id 0..3
    const int l   = t & 63;
    const int r   = l & 15;            // A row (oc), B col (pos), within tile
    const int kb  = l >> 4;            // k-block 0..3
    const float* arow = Wc + (w_s * 16 + r) * 576 + kb * 8;

    f32x4 acc0 = {0.f, 0.f, 0.f, 0.f};
    f32x4 acc1 = {0.f, 0.f, 0.f, 0.f};

    auto mfma_chunk = [&](int cb, int dbase) {
#pragma unroll 3
        for (int s = 0; s < 9; ++s) {
            const float* ap = arow + cb + s * 32;
            const float4 alo = *(const float4*)ap;
            const float4 ahi = *(const float4*)(ap + 4);
            bf16x8 af;
            af[0] = (short)bfbits(alo.x); af[1] = (short)bfbits(alo.y);
            af[2] = (short)bfbits(alo.z); af[3] = (short)bfbits(alo.w);
            af[4] = (short)bfbits(ahi.x); af[5] = (short)bfbits(ahi.y);
            af[6] = (short)bfbits(ahi.z); af[7] = (short)bfbits(ahi.w);
            const unsigned short* bp0 = bbuf + dbase + ((s * 4 + kb) << 8) + (r << 3);
            const bf16x8 bf0 = *(const bf16x8*)bp0;          // tile pos 0..15
            const bf16x8 bf1 = *(const bf16x8*)(bp0 + 128);  // tile pos 16..31
            acc0 = __builtin_amdgcn_mfma_f32_16x16x32_bf16(af, bf0, acc0, 0, 0, 0);
            acc1 = __builtin_amdgcn_mfma_f32_16x16x32_bf16(af, bf1, acc1, 0, 0, 0);
        }
    };

    stage(0, 0);                 // chunk 0 -> buf 0
    __syncthreads();
    mfma_chunk(0, 0);            // consume buf 0 (ds_reads first in lgkm order)
    stage(32, 9216);             // chunk 1 -> buf 1
    __syncthreads();
    mfma_chunk(288, 9216);       // consume buf 1

    // epilogue: C/D layout col=lane&15 (pos), row=(lane>>4)*4+reg (oc)
    const int ocb = b * OC + w_s * 16;
#pragma unroll
    for (int reg = 0; reg < 4; ++reg) {
        const int oc = ocb + (l >> 4) * 4 + reg;
        float* o = out + (oc * HH + i) * WW + j0;
        o[r]      = acc0[reg];
        o[16 + r] = acc1[reg];
    }
}

extern "C" void kernel_launch(void* const* d_in, const int* in_sizes, int n_in,
                              void* d_out, int out_size, void* d_ws, size_t ws_size,
                              hipStream_t stream) {
    const float* x  = (const float*)d_in[0];
    const float* Wp = (const float*)d_in[1];
    const float* bp = (const float*)d_in[2];
    const float* Wc = (const float*)d_in[3];
    float* out = (float*)d_out;
    dcn_mfma<<<dim3(BB * HH * 4), dim3(256), 0, stream>>>(x, Wp, bp, Wc, out);
}